// Round 4
// baseline (446.328 us; speedup 1.0000x reference)
//
#include <hip/hip_runtime.h>

// Problem constants (from reference)
#define B_     8
#define L_DEC_ 256
#define V_     32000
#define L_SRC_ 512
#define V_EXT_ 32128

#define V4_    (V_ / 4)        // 8000 float4 per dist row
#define VE4_   (V_EXT_ / 4)    // 8032 float4 per out row

#define NMAIN_   15            // k=0..14: i in [0,7680), fully inside dist
#define TAIL_I0_ (NMAIN_ * 512)      // 7680
#define TAIL_N_  (VE4_ - TAIL_I0_)   // 352 active threads in tail
#define TAIL_ND_ (V4_  - TAIL_I0_)   // 320 of them still inside dist

// Native clang vector type (16 B/lane loads/stores).
typedef float f32x4 __attribute__((ext_vector_type(4)));

// Fused kernel, one block per (b,t) output row:
//   out[b,t,v] = p_gen*dist[v] (v<V, else 0) + (1-p_gen)*copyp[v]
//   copyp[v]   = sum_{s: pointer[b,s]==v} alpha[b,s,t]
//
// v4 (A/B vs v3): NT hints removed (regular loads/stores — the 6.3-6.5 TB/s
// reference patterns on this chip are non-NT); k=15 tail peeled so the main
// loop is branch-free; per-iteration LDS list-walk replaced by a register
// slot-mask (bit k set iff this thread has a scatter entry in iteration k),
// so the hot loop is pure load->fma->store + one bit test.
__global__ __launch_bounds__(512, 8) void copynet_fused(
    const float* __restrict__ dist,    // [B, L_DEC, V]
    const float* __restrict__ p_gen,   // [B, L_DEC, 1]
    const float* __restrict__ alph,    // [B, L_SRC, L_DEC]
    const int*   __restrict__ pointer, // [B, L_SRC]
    float* __restrict__ out)           // [B, L_DEC, V_EXT]
{
    __shared__ int   head[512];   // per-owner-thread list head (-1 = empty)
    __shared__ int   nxt[512];    // linkage, indexed by entry id (= s)
    __shared__ int   key[512];    // vocab index v of entry
    __shared__ float sval[512];   // (1-pg)*alpha value of entry

    const int row = blockIdx.x;   // b*L_DEC + t  (t fastest -> alpha L2 reuse)
    const int b   = row >> 8;     // / L_DEC
    const int t   = row & (L_DEC_ - 1);
    const int tid = threadIdx.x;  // 0..511

    const float pg   = p_gen[row];
    const float coef = 1.0f - pg;

    // This thread's scatter entry: s == tid (L_SRC == blockDim == 512).
    // alpha[b] is 512 KB, reused across 256 t-rows -> L2/L3 resident.
    const int   sIdx = b * L_SRC_ + tid;
    const int   v    = pointer[sIdx];
    const float val  = coef * alph[(size_t)sIdx * L_DEC_ + t];

    // Bucket the 512 (v,val) pairs by owner thread of their float4 slot:
    // slot i = v>>2 is written by thread i&511 in iteration i>>9.
    head[tid] = -1;
    __syncthreads();
    key[tid]  = v;
    sval[tid] = val;
    const int owner = (v >> 2) & 511;
    nxt[tid] = atomicExch(&head[owner], tid);   // lock-free stack push (ds op)
    __syncthreads();

    const int myHead = head[tid];               // immutable after barrier
    // One upfront walk: which iterations have a hit for this thread?
    unsigned mask = 0u;
    for (int e = myHead; e != -1; e = nxt[e])
        mask |= 1u << (key[e] >> 11);           // k = (v>>2) >> 9

    const f32x4* dist4 = (const f32x4*)(dist + (size_t)row * V_);
    f32x4*       out4  = (f32x4*)(out + (size_t)row * V_EXT_);

    // Branch-free main stream: 15 x (load16B -> scale -> store16B).
#pragma unroll
    for (int k = 0; k < NMAIN_; ++k) {
        const int i = tid + (k << 9);
        f32x4 r = dist4[i] * pg;
        if (mask & (1u << k)) {                 // rare (~1 hit/thread total)
            for (int e = myHead; e != -1; e = nxt[e]) {
                const int kv = key[e];
                if ((kv >> 2) == i) {
                    const float a = sval[e];
                    const int   c = kv & 3;
                    r.x += (c == 0) ? a : 0.f;
                    r.y += (c == 1) ? a : 0.f;
                    r.z += (c == 2) ? a : 0.f;
                    r.w += (c == 3) ? a : 0.f;
                }
            }
        }
        out4[i] = r;
    }

    // Peeled tail (k = 15): dist/pad boundary and row end both live here.
    if (tid < TAIL_N_) {
        const int i = TAIL_I0_ + tid;
        f32x4 r = {0.f, 0.f, 0.f, 0.f};
        if (tid < TAIL_ND_)
            r = dist4[i] * pg;
        if (mask & (1u << 15)) {
            for (int e = myHead; e != -1; e = nxt[e]) {
                const int kv = key[e];
                if ((kv >> 2) == i) {
                    const float a = sval[e];
                    const int   c = kv & 3;
                    r.x += (c == 0) ? a : 0.f;
                    r.y += (c == 1) ? a : 0.f;
                    r.z += (c == 2) ? a : 0.f;
                    r.w += (c == 3) ? a : 0.f;
                }
            }
        }
        out4[i] = r;
    }
}

extern "C" void kernel_launch(void* const* d_in, const int* in_sizes, int n_in,
                              void* d_out, int out_size, void* d_ws, size_t ws_size,
                              hipStream_t stream)
{
    const float* dist    = (const float*)d_in[0]; // (B, L_DEC, V)
    const float* p_gen   = (const float*)d_in[1]; // (B, L_DEC, 1)
    const float* alph    = (const float*)d_in[2]; // (B, L_SRC, L_DEC)
    // d_in[3] = batch_vocab (shape only)
    const int*   pointer = (const int*)d_in[4];   // (B, L_SRC)
    float* out = (float*)d_out;                   // (B, L_DEC, V_EXT)

    copynet_fused<<<B_ * L_DEC_, 512, 0, stream>>>(dist, p_gen, alph, pointer, out);
}